// Round 15
// baseline (203.923 us; speedup 1.0000x reference)
//
#include <hip/hip_runtime.h>
#include <stdint.h>

#define LL 16384
#define NB 2
#define CIN 96
#define NLAT 256
#define COUT 96
#define NCH 256   // scan chunks per direction
#define CHU 64    // positions per chunk

typedef __attribute__((ext_vector_type(8))) short short8v;
typedef __attribute__((ext_vector_type(4))) float float4v;

__device__ __forceinline__ float b2f(unsigned short h) {
    return __uint_as_float(((unsigned int)h) << 16);
}
__device__ __forceinline__ unsigned short f2b(float f) {
    unsigned int u = __float_as_uint(f);
    unsigned int r = (u + 0x7FFFu + ((u >> 16) & 1u)) >> 16;
    return (unsigned short)r;
}

#define GLL16(g, s) __builtin_amdgcn_global_load_lds( \
    (const __attribute__((address_space(1))) unsigned int*)(g), \
    (__attribute__((address_space(3))) unsigned int*)(s), 16, 0, 0)

// ---------------- fold weights, split-K partials
__global__ __launch_bounds__(256) void k_foldw_part(
    const float* __restrict__ yw, const float* __restrict__ mw, const float* __restrict__ gw,
    float* __restrict__ WF)
{
    __shared__ float At[64][68];
    __shared__ float Bt[64][68];
    int jt = blockIdx.x, nt = blockIdx.y, dzk = blockIdx.z;
    int kc = dzk & 3, dz = dzk >> 2;
    int d = dz & 3, mat = dz >> 2;
    const float* src = mat ? gw : mw;
    int j0 = jt * 64, n0 = nt * 64;
    int tid = threadIdx.x, tx = tid & 15, ty = tid >> 4;
    float acc[4][4] = {};
    int i0 = kc * 64;
    for (int rep = 0; rep < 16; ++rep) {
        int idx = rep * 256 + tid;
        int r = idx >> 6, cq = idx & 63;
        At[r][cq] = yw[(size_t)(i0 + r) * 256 + j0 + cq];
        Bt[cq][r] = src[(size_t)(n0 + r) * 1024 + d * 256 + i0 + cq];
    }
    __syncthreads();
    for (int ii = 0; ii < 64; ++ii) {
        float4 a4 = *(const float4*)(&At[ii][ty * 4]);
        float4 b4 = *(const float4*)(&Bt[ii][tx * 4]);
        float av[4] = {a4.x, a4.y, a4.z, a4.w};
        float bv[4] = {b4.x, b4.y, b4.z, b4.w};
        for (int q = 0; q < 4; ++q)
            for (int p = 0; p < 4; ++p)
                acc[q][p] = fmaf(av[q], bv[p], acc[q][p]);
    }
    float* dst = WF + (size_t)kc * 512 * 1024;
    for (int q = 0; q < 4; ++q) {
        int k = d * 256 + j0 + ty * 4 + q;
        for (int p = 0; p < 4; ++p) {
            int n = n0 + tx * 4 + p;
            dst[(size_t)(mat * 256 + n) * 1024 + k] = acc[q][p];
        }
    }
}

// sum the 4 split-K partials, round to bf16
__global__ __launch_bounds__(256) void k_foldsum(
    const float* __restrict__ WF, unsigned short* __restrict__ WBT)
{
    int t = blockIdx.x * 256 + threadIdx.x;
    size_t o = (size_t)t * 4;
    const size_t S = (size_t)512 * 1024;
    float4 s0 = *(const float4*)(WF + o);
    float4 s1 = *(const float4*)(WF + S + o);
    float4 s2 = *(const float4*)(WF + 2 * S + o);
    float4 s3 = *(const float4*)(WF + 3 * S + o);
    unsigned short pk[4];
    pk[0] = f2b(s0.x + s1.x + s2.x + s3.x);
    pk[1] = f2b(s0.y + s1.y + s2.y + s3.y);
    pk[2] = f2b(s0.z + s1.z + s2.z + s3.z);
    pk[3] = f2b(s0.w + s1.w + s2.w + s3.w);
    *(unsigned long long*)(&WBT[o]) = *(const unsigned long long*)pk;
}

// ---------------- fused prep: xpose (512) | wprep (32) | owprep (32) | foldbias (128)
__global__ __launch_bounds__(256) void k_prep(
    const float* __restrict__ x, unsigned short* __restrict__ XT,
    const float* __restrict__ xw, const float* __restrict__ bcw, const float* __restrict__ dw,
    unsigned short* __restrict__ WPT,
    const float* __restrict__ ow, unsigned short* __restrict__ OWB,
    const float* __restrict__ mw, const float* __restrict__ gw,
    const float* __restrict__ mb, const float* __restrict__ gb,
    const float* __restrict__ yb,
    float* __restrict__ bm2, float* __restrict__ bg2)
{
    int bid = blockIdx.x;
    int t = threadIdx.x;
    if (bid < 512) {
        int pl = t & 63;
        int grp = t >> 6;
        int p0 = bid * 64;
        int b = p0 >> 14;
        int l = (p0 & (LL - 1)) + pl;
        size_t gp = (size_t)(p0 + pl);
        const float* xr = x + (size_t)b * 96 * LL + l;
        unsigned short* orow = XT + gp * 192;
#pragma unroll
        for (int kk = 0; kk < 3; ++kk) {
            int kq = grp * 3 + kk;
            short8v hi, lo;
#pragma unroll
            for (int c = 0; c < 8; ++c) {
                float v = xr[(size_t)(kq * 8 + c) * LL];
                unsigned short h = f2b(v);
                float r = v - b2f(h);
                hi[c] = (short)h;
                lo[c] = (short)f2b(r);
            }
            *(short8v*)(orow + kq * 8) = hi;
            *(short8v*)(orow + 96 + kq * 8) = lo;
        }
    } else if (bid < 544) {
        int unit = bid - 512;
        int rp = unit * 32 + (t >> 3);
        int sub = t & 7;
        int nn16 = rp >> 6, g = (rp >> 4) & 3, ni = rp & 15;
        int n = nn16 * 16 + ni;
        const float* row;
        if (g == 0)      row = xw + (size_t)n * 96;
        else if (g == 1) row = bcw + (size_t)n * 96;
        else if (g == 2) row = bcw + (size_t)(256 + n) * 96;
        else             row = dw + (size_t)n * 96;
        unsigned short* orow = WPT + (size_t)rp * 192;
        for (int kq = sub; kq < 12; kq += 8) {
            short8v hv;
#pragma unroll
            for (int c = 0; c < 8; ++c) hv[c] = (short)f2b(row[kq * 8 + c]);
            *(short8v*)(orow + kq * 8) = hv;
            *(short8v*)(orow + 96 + kq * 8) = hv;
        }
    } else if (bid < 576) {
        int unit = bid - 544;
        int r = unit * 4 + (t >> 6);
        int lane = t & 63;
        unsigned short pk[4];
        if (r < 96) {
            float4 v = *(const float4*)(ow + (size_t)r * 256 + lane * 4);
            pk[0] = f2b(v.x); pk[1] = f2b(v.y); pk[2] = f2b(v.z); pk[3] = f2b(v.w);
        } else {
            pk[0] = pk[1] = pk[2] = pk[3] = 0;
        }
        *(unsigned long long*)(&OWB[(size_t)r * 256 + lane * 4]) = *(const unsigned long long*)pk;
    } else {
        int unit = bid - 576;
        int row = unit * 4 + (t >> 6);
        int lane = t & 63;
        int n = row & 255;
        const float* W = (row < 256) ? mw : gw;
        float s = 0.f;
        for (int k = lane; k < 1024; k += 64)
            s = fmaf(W[(size_t)n * 1024 + k], yb[k & 255], s);
        for (int off = 32; off; off >>= 1) s += __shfl_down(s, off);
        if (lane == 0) {
            if (row < 256) bm2[n] = s + mb[n];
            else           bg2[n] = s + gb[n];
        }
    }
}

// ---------------- in-projection via MFMA (K=192), dbuf + counted vmcnt (r10 pattern)
__global__ __launch_bounds__(256) void k_proj_mfma(
    const unsigned short* __restrict__ XT, const unsigned short* __restrict__ WPT,
    const float* __restrict__ xb, const float* __restrict__ bcb, const float* __restrict__ db,
    unsigned int* __restrict__ AB, unsigned short* __restrict__ C)
{
    __shared__ __align__(16) unsigned short smA[2 * 128 * 32];   // 16 KB
    __shared__ __align__(16) unsigned short smB[2 * 128 * 32];   // 16 KB
    int tid = threadIdx.x;
    int w = tid >> 6, l = tid & 63;
    int mt = blockIdx.x;
    int bnt = blockIdx.y;
    int p0 = mt * 128;
    int bn0 = bnt * 128;

    int rowA = tid >> 2;
    int chA  = tid & 3;
    int laneRow = l & 15;
    int laneK   = l >> 4;

    float4v acc[2][8];
#pragma unroll
    for (int i = 0; i < 2; ++i)
#pragma unroll
        for (int f = 0; f < 8; ++f) acc[i][f] = (float4v)0.f;

    auto stage = [&](int kt, int buf) {
        const unsigned short* gA = XT + (size_t)(p0 + rowA) * 192 + kt * 32 + chA * 8;
        const unsigned short* gB = WPT + (size_t)(bn0 + rowA) * 192 + kt * 32 + chA * 8;
        unsigned short* sA = smA + buf * 4096;
        unsigned short* sB = smB + buf * 4096;
        GLL16(gA,            sA + tid * 8);
        GLL16(gA + 64 * 192, sA + 2048 + tid * 8);
        GLL16(gB,            sB + tid * 8);
        GLL16(gB + 64 * 192, sB + 2048 + tid * 8);
    };

    stage(0, 0);

    int cur = 0;
    for (int kt = 0; kt < 6; ++kt) {
        if (kt < 5) {
            stage(kt + 1, cur ^ 1);
            asm volatile("s_waitcnt vmcnt(4)" ::: "memory");
        } else {
            asm volatile("s_waitcnt vmcnt(0)" ::: "memory");
        }
        __builtin_amdgcn_s_barrier();

        const unsigned short* sA = smA + cur * 4096;
        const unsigned short* sB = smB + cur * 4096;
        short8v a0 = *(const short8v*)(&sA[(w * 32 + laneRow) * 32 + laneK * 8]);
        short8v a1 = *(const short8v*)(&sA[(w * 32 + 16 + laneRow) * 32 + laneK * 8]);
#pragma unroll
        for (int f = 0; f < 8; ++f) {
            short8v bf_ = *(const short8v*)(&sB[(f * 16 + laneRow) * 32 + laneK * 8]);
            acc[0][f] = __builtin_amdgcn_mfma_f32_16x16x32_bf16(a0, bf_, acc[0][f], 0, 0, 0);
            acc[1][f] = __builtin_amdgcn_mfma_f32_16x16x32_bf16(a1, bf_, acc[1][f], 0, 0, 0);
        }
        __builtin_amdgcn_s_barrier();
        cur ^= 1;
    }

    int lr = l >> 4, lc = l & 15;
#pragma unroll
    for (int mr = 0; mr < 2; ++mr) {
#pragma unroll
        for (int nn2 = 0; nn2 < 2; ++nn2) {
            int n = (bnt * 2 + nn2) * 16 + lc;
            float xbv = xb[n], bb = bcb[n], cb = bcb[256 + n], dbv = db[n];
#pragma unroll
            for (int q = 0; q < 4; ++q) {
                int p = p0 + w * 32 + mr * 16 + lr * 4 + q;
                float u  = acc[mr][nn2 * 4 + 0][q] + xbv;
                float Bm = acc[mr][nn2 * 4 + 1][q] + bb;
                float Cm = acc[mr][nn2 * 4 + 2][q] + cb;
                float dl = acc[mr][nn2 * 4 + 3][q] + dbv;
                float a  = 1.0f / (1.0f + __expf(dl));
                float bu = (1.0f - a) * Bm * u;
                size_t base = (size_t)p * NLAT + n;
                AB[base] = (unsigned int)f2b(a) | ((unsigned int)f2b(bu) << 16);
                C[base]  = f2b(Cm);
            }
        }
    }
}

__device__ __forceinline__ int src_pos(int d, int t) {
    int s = (d >= 2) ? (LL - 1 - t) : t;
    return (d & 1) ? (((s & 127) << 7) | (s >> 7)) : s;
}

// ---------------- scan pass 1: dir-paired, ILP-2
__global__ __launch_bounds__(256) void k_scan1(
    const unsigned int* __restrict__ AB,
    float* __restrict__ AggA, float* __restrict__ AggB)
{
    int n = threadIdx.x;
    int c = blockIdx.x, dp = blockIdx.y, b = blockIdx.z;
    int d1 = dp, d2 = dp + 2;
    int c2 = NCH - 1 - c;
    int t01 = c * CHU, t02 = c2 * CHU;
    const unsigned int* ABb = AB + (size_t)b * LL * NLAT + n;
    float h1 = 0.f, A1 = 1.f, h2 = 0.f, A2 = 1.f;
#pragma unroll 4
    for (int i = 0; i < CHU; ++i) {
        int ls1 = src_pos(d1, t01 + i);
        int ls2 = src_pos(d2, t02 + i);
        unsigned int v1 = ABb[(size_t)ls1 * NLAT];
        unsigned int v2 = ABb[(size_t)ls2 * NLAT];
        float a1 = __uint_as_float(v1 << 16), bu1 = __uint_as_float(v1 & 0xFFFF0000u);
        float a2 = __uint_as_float(v2 << 16), bu2 = __uint_as_float(v2 & 0xFFFF0000u);
        h1 = fmaf(a1, h1, bu1); A1 *= a1;
        h2 = fmaf(a2, h2, bu2); A2 *= a2;
    }
    size_t o1 = (((size_t)b * 4 + d1) * NCH + c) * NLAT + n;
    size_t o2 = (((size_t)b * 4 + d2) * NCH + c2) * NLAT + n;
    AggA[o1] = A1; AggB[o1] = h1;
    AggA[o2] = A2; AggB[o2] = h2;
}

// ---------------- scan pass 2: Kogge-Stone over NCH chunk-aggregate affine maps
__global__ __launch_bounds__(256) void k_scan2(
    const float* __restrict__ AggA, const float* __restrict__ AggB,
    float* __restrict__ Hs)
{
    __shared__ float sA[NCH];
    __shared__ float sB[NCH];
    int n = blockIdx.x;
    int d = blockIdx.y, b = blockIdx.z;
    int c = threadIdx.x;
    size_t o = (((size_t)b * 4 + d) * NCH + c) * NLAT + n;
    sA[c] = AggA[o];
    sB[c] = AggB[o];
    __syncthreads();
#pragma unroll
    for (int st = 1; st < NCH; st <<= 1) {
        float pA = 1.f, pB = 0.f;
        if (c >= st) { pA = sA[c - st]; pB = sB[c - st]; }
        __syncthreads();
        if (c >= st) {
            float aO = sA[c];
            sB[c] = fmaf(aO, pB, sB[c]);
            sA[c] = aO * pA;
        }
        __syncthreads();
    }
    Hs[o] = (c == 0) ? 0.f : sB[c - 1];
}

// ---------------- scan pass 3: dir-paired replay, ILP-2, y = C*h
__global__ __launch_bounds__(256) void k_scan3(
    const unsigned int* __restrict__ AB, const unsigned short* __restrict__ C,
    const float* __restrict__ Hs, unsigned short* __restrict__ ys)
{
    int n = threadIdx.x;
    int c = blockIdx.x, dp = blockIdx.y, b = blockIdx.z;
    int d1 = dp, d2 = dp + 2;
    int c2 = NCH - 1 - c;
    int t01 = c * CHU, t02 = c2 * CHU;
    const unsigned int* ABb = AB + (size_t)b * LL * NLAT + n;
    const unsigned short* Cb = C + (size_t)b * LL * NLAT + n;
    size_t o1 = (((size_t)b * 4 + d1) * NCH + c) * NLAT + n;
    size_t o2 = (((size_t)b * 4 + d2) * NCH + c2) * NLAT + n;
    float h1 = Hs[o1], h2 = Hs[o2];
    size_t yb1 = (((size_t)b * 4 + d1) * LL + t01) * NLAT + n;
    size_t yb2 = (((size_t)b * 4 + d2) * LL + t02) * NLAT + n;
#pragma unroll 4
    for (int i = 0; i < CHU; ++i) {
        int ls1 = src_pos(d1, t01 + i);
        int ls2 = src_pos(d2, t02 + i);
        size_t i1 = (size_t)ls1 * NLAT, i2 = (size_t)ls2 * NLAT;
        unsigned int v1 = ABb[i1];
        unsigned int v2 = ABb[i2];
        float a1 = __uint_as_float(v1 << 16), bu1 = __uint_as_float(v1 & 0xFFFF0000u);
        float a2 = __uint_as_float(v2 << 16), bu2 = __uint_as_float(v2 & 0xFFFF0000u);
        h1 = fmaf(a1, h1, bu1);
        h2 = fmaf(a2, h2, bu2);
        float y1 = b2f(Cb[i1]) * h1;
        float y2 = b2f(Cb[i2]) * h2;
        ys[yb1 + (size_t)i * NLAT] = f2b(y1);
        ys[yb2 + (size_t)i * NLAT] = f2b(y2);
    }
}

// ---------------- merge (MFMA bf16) — r11 template + 3-deep prefetch (vmcnt(12))
__global__ __launch_bounds__(256) void k_merge_mfma(
    const unsigned short* __restrict__ ys,
    const unsigned short* __restrict__ WBT,
    const float* __restrict__ bm2, const float* __restrict__ bg2,
    unsigned short* __restrict__ z)
{
    __shared__ __align__(16) unsigned short smA[3 * 128 * 32];   // 24 KB
    __shared__ __align__(16) unsigned short smB[3 * 256 * 32];   // 48 KB
    int tid = threadIdx.x;
    int w = tid >> 6, l = tid & 63;
    int wm = w >> 1, wn = w & 1;
    int mt = blockIdx.x;
    int nt = blockIdx.y;
    int p0 = mt * 128;
    int b4 = (p0 >> 14) * 4;
    int l0 = p0 & (LL - 1);
    int n0 = nt * 128;

    int rS = tid >> 2;
    int cg = (tid & 3) ^ ((rS >> 1) & 3);
    int laneRow = l & 15;
    int laneK   = l >> 4;
    int rx = (laneRow >> 1) & 3;

    float4v accM[4][4], accG[4][4];
#pragma unroll
    for (int i = 0; i < 4; ++i)
#pragma unroll
        for (int j = 0; j < 4; ++j) { accM[i][j] = (float4v)0.f; accG[i][j] = (float4v)0.f; }

    auto stage = [&](int kt, int buf) {
        int d = kt >> 3;
        int j0k = (kt & 7) * 32;
        const unsigned short* gAb = ys + (((size_t)(b4 + d)) * LL + l0) * 256 + j0k + cg * 8;
        unsigned short* sA = smA + buf * 4096;
        unsigned short* sB = smB + buf * 8192;
#pragma unroll
        for (int rep = 0; rep < 2; ++rep) {
            GLL16(gAb + (size_t)(rep * 64 + rS) * 256, sA + rep * 2048 + tid * 8);
        }
#pragma unroll
        for (int rep = 0; rep < 4; ++rep) {
            int rr = rep * 64 + rS;
            int nrow = (rr < 128) ? (n0 + rr) : (256 + n0 + rr - 128);
            GLL16(WBT + (size_t)nrow * 1024 + kt * 32 + cg * 8, sB + rep * 2048 + tid * 8);
        }
    };

    stage(0, 0);
    stage(1, 1);

    for (int kt = 0; kt < 32; ++kt) {
        int cb = kt % 3;
        if (kt < 30) {
            stage(kt + 2, (kt + 2) % 3);
            asm volatile("s_waitcnt vmcnt(12)" ::: "memory");   // kt's 6 loads done; kt+1,kt+2 in flight
        } else if (kt == 30) {
            asm volatile("s_waitcnt vmcnt(6)" ::: "memory");
        } else {
            asm volatile("s_waitcnt vmcnt(0)" ::: "memory");
        }
        __builtin_amdgcn_s_barrier();

        const unsigned short* sA = smA + cb * 4096;
        const unsigned short* sB = smB + cb * 8192;
        int cxo = (laneK ^ rx) * 8;
        short8v a[4];
#pragma unroll
        for (int mr = 0; mr < 4; ++mr)
            a[mr] = *(const short8v*)(&sA[(wm * 64 + mr * 16 + laneRow) * 32 + cxo]);
#pragma unroll
        for (int nr = 0; nr < 4; ++nr) {
            short8v bm_ = *(const short8v*)(&sB[(wn * 64 + nr * 16 + laneRow) * 32 + cxo]);
            short8v bg_ = *(const short8v*)(&sB[(128 + wn * 64 + nr * 16 + laneRow) * 32 + cxo]);
#pragma unroll
            for (int mr = 0; mr < 4; ++mr) {
                accM[mr][nr] = __builtin_amdgcn_mfma_f32_16x16x32_bf16(a[mr], bm_, accM[mr][nr], 0, 0, 0);
                accG[mr][nr] = __builtin_amdgcn_mfma_f32_16x16x32_bf16(a[mr], bg_, accG[mr][nr], 0, 0, 0);
            }
        }
        __builtin_amdgcn_s_barrier();
    }

    int lr = l >> 4, lc = l & 15;
#pragma unroll
    for (int mr = 0; mr < 4; ++mr) {
#pragma unroll
        for (int nr = 0; nr < 4; ++nr) {
            int n = n0 + wn * 64 + nr * 16 + lc;
            float bmv = bm2[n], bgv = bg2[n];
#pragma unroll
            for (int q = 0; q < 4; ++q) {
                int p = p0 + wm * 64 + mr * 16 + lr * 4 + q;
                float m = accM[mr][nr][q] + bmv;
                float g = accG[mr][nr][q] + bgv;
                float zv = m / (1.f + __expf(-g));
                z[(size_t)p * NLAT + n] = f2b(zv);
            }
        }
    }
}

// ---------------- out projection via MFMA (K=256), dbuf + counted vmcnt
__global__ __launch_bounds__(256) void k_out_mfma(
    const unsigned short* __restrict__ z, const unsigned short* __restrict__ OWB,
    const float* __restrict__ ob, float* __restrict__ out)
{
    __shared__ __align__(16) unsigned short smA[2 * 128 * 32];
    __shared__ __align__(16) unsigned short smB[2 * 128 * 32];
    int tid = threadIdx.x;
    int w = tid >> 6, l = tid & 63;
    int p0 = blockIdx.x * 128;
    int b = p0 >> 14;
    int l0 = p0 & (LL - 1);

    int rowA = tid >> 2;
    int chA  = tid & 3;
    int laneRow = l & 15;
    int laneK   = l >> 4;

    float4v acc[2][6];
#pragma unroll
    for (int i = 0; i < 2; ++i)
#pragma unroll
        for (int f = 0; f < 6; ++f) acc[i][f] = (float4v)0.f;

    auto stage = [&](int kt, int buf) {
        const unsigned short* gA = z + (size_t)(p0 + rowA) * 256 + kt * 32 + chA * 8;
        const unsigned short* gB = OWB + (size_t)rowA * 256 + kt * 32 + chA * 8;
        unsigned short* sA = smA + buf * 4096;
        unsigned short* sB = smB + buf * 4096;
        GLL16(gA,            sA + tid * 8);
        GLL16(gA + 64 * 256, sA + 2048 + tid * 8);
        GLL16(gB,            sB + tid * 8);
        GLL16(gB + 64 * 256, sB + 2048 + tid * 8);
    };

    stage(0, 0);

    int cur = 0;
    for (int kt = 0; kt < 8; ++kt) {
        if (kt < 7) {
            stage(kt + 1, cur ^ 1);
            asm volatile("s_waitcnt vmcnt(4)" ::: "memory");
        } else {
            asm volatile("s_waitcnt vmcnt(0)" ::: "memory");
        }
        __builtin_amdgcn_s_barrier();

        const unsigned short* sA = smA + cur * 4096;
        const unsigned short* sB = smB + cur * 4096;
        short8v a0 = *(const short8v*)(&sA[(w * 32 + laneRow) * 32 + laneK * 8]);
        short8v a1 = *(const short8v*)(&sA[(w * 32 + 16 + laneRow) * 32 + laneK * 8]);
#pragma unroll
        for (int nr = 0; nr < 6; ++nr) {
            short8v bf_ = *(const short8v*)(&sB[(nr * 16 + laneRow) * 32 + laneK * 8]);
            acc[0][nr] = __builtin_amdgcn_mfma_f32_16x16x32_bf16(a0, bf_, acc[0][nr], 0, 0, 0);
            acc[1][nr] = __builtin_amdgcn_mfma_f32_16x16x32_bf16(a1, bf_, acc[1][nr], 0, 0, 0);
        }
        __builtin_amdgcn_s_barrier();
        cur ^= 1;
    }

    int lr = l >> 4, lc = l & 15;
#pragma unroll
    for (int mr = 0; mr < 2; ++mr) {
#pragma unroll
        for (int nr = 0; nr < 6; ++nr) {
            int c = nr * 16 + lc;
            float obv = ob[c];
            int ll = l0 + w * 32 + mr * 16 + lr * 4;
            float4 v;
            v.x = acc[mr][nr][0] + obv;
            v.y = acc[mr][nr][1] + obv;
            v.z = acc[mr][nr][2] + obv;
            v.w = acc[mr][nr][3] + obv;
            *(float4*)(&out[((size_t)(b * 96 + c)) * LL + ll]) = v;
        }
    }
}

extern "C" void kernel_launch(void* const* d_in, const int* in_sizes, int n_in,
                              void* d_out, int out_size, void* d_ws, size_t ws_size,
                              hipStream_t stream) {
    (void)in_sizes; (void)n_in; (void)out_size; (void)ws_size;
    const float* x   = (const float*)d_in[0];
    const float* xw  = (const float*)d_in[1];
    const float* xb  = (const float*)d_in[2];
    const float* bcw = (const float*)d_in[3];
    const float* bcb = (const float*)d_in[4];
    const float* dw  = (const float*)d_in[5];
    const float* db  = (const float*)d_in[6];
    const float* yw  = (const float*)d_in[7];
    const float* yb  = (const float*)d_in[8];
    const float* mw  = (const float*)d_in[9];
    const float* mb  = (const float*)d_in[10];
    const float* gw  = (const float*)d_in[11];
    const float* gb  = (const float*)d_in[12];
    const float* ow  = (const float*)d_in[13];
    const float* ob  = (const float*)d_in[14];
    float* out = (float*)d_out;

    char* ws = (char*)d_ws;
    size_t off = 0;
    auto alloc = [&](size_t bytes) -> void* {
        void* p = ws + off;
        off += (bytes + 255) & ~(size_t)255;
        return p;
    };
    unsigned int*   AB  = (unsigned int*)  alloc((size_t)NB * LL * NLAT * 4);
    unsigned short* C   = (unsigned short*)alloc((size_t)NB * LL * NLAT * 2);
    unsigned short* YS  = (unsigned short*)alloc((size_t)NB * 4 * LL * NLAT * 2);
    unsigned short* Z   = (unsigned short*)alloc((size_t)NB * LL * NLAT * 2);
    unsigned short* WBT = (unsigned short*)alloc((size_t)512 * 1024 * 2);
    unsigned short* XT  = (unsigned short*)alloc((size_t)NB * LL * 192 * 2);
    unsigned short* WPT = (unsigned short*)alloc((size_t)1024 * 192 * 2);
    unsigned short* OWB = (unsigned short*)alloc((size_t)128 * 256 * 2);
    float* WF   = (float*)alloc((size_t)4 * 512 * 1024 * 4);
    float* BM2  = (float*)alloc(256 * 4);
    float* BG2  = (float*)alloc(256 * 4);
    float* AggA = (float*)alloc((size_t)NB * 4 * NCH * NLAT * 4);
    float* AggB = (float*)alloc((size_t)NB * 4 * NCH * NLAT * 4);
    float* HS   = (float*)alloc((size_t)NB * 4 * NCH * NLAT * 4);

    k_foldw_part<<<dim3(4, 4, 32),    256, 0, stream>>>(yw, mw, gw, WF);
    k_foldsum   <<<512,               256, 0, stream>>>(WF, WBT);
    k_prep      <<<704,               256, 0, stream>>>(x, XT, xw, bcw, dw, WPT,
                                                        ow, OWB, mw, gw, mb, gb, yb, BM2, BG2);
    k_proj_mfma <<<dim3(256, 8),      256, 0, stream>>>(XT, WPT, xb, bcb, db, AB, C);
    k_scan1     <<<dim3(NCH, 2, NB),  256, 0, stream>>>(AB, AggA, AggB);
    k_scan2     <<<dim3(NLAT, 4, NB), 256, 0, stream>>>(AggA, AggB, HS);
    k_scan3     <<<dim3(NCH, 2, NB),  256, 0, stream>>>(AB, C, HS, YS);
    k_merge_mfma<<<dim3(256, 2),      256, 0, stream>>>(YS, WBT, BM2, BG2, Z);
    k_out_mfma  <<<256,               256, 0, stream>>>(Z, OWB, ob, out);
}

// Round 16
// 176.704 us; speedup vs baseline: 1.1540x; 1.1540x over previous
//
#include <hip/hip_runtime.h>
#include <stdint.h>

#define LL 16384
#define NB 2
#define CIN 96
#define NLAT 256
#define COUT 96
#define NCH 256   // scan chunks per direction
#define CHU 64    // positions per chunk

typedef __attribute__((ext_vector_type(8))) short short8v;
typedef __attribute__((ext_vector_type(4))) float float4v;

__device__ __forceinline__ float b2f(unsigned short h) {
    return __uint_as_float(((unsigned int)h) << 16);
}
__device__ __forceinline__ unsigned short f2b(float f) {
    unsigned int u = __float_as_uint(f);
    unsigned int r = (u + 0x7FFFu + ((u >> 16) & 1u)) >> 16;
    return (unsigned short)r;
}

#define GLL16(g, s) __builtin_amdgcn_global_load_lds( \
    (const __attribute__((address_space(1))) unsigned int*)(g), \
    (__attribute__((address_space(3))) unsigned int*)(s), 16, 0, 0)

// ---------------- fold weights, split-K partials
__global__ __launch_bounds__(256) void k_foldw_part(
    const float* __restrict__ yw, const float* __restrict__ mw, const float* __restrict__ gw,
    float* __restrict__ WF)
{
    __shared__ float At[64][68];
    __shared__ float Bt[64][68];
    int jt = blockIdx.x, nt = blockIdx.y, dzk = blockIdx.z;
    int kc = dzk & 3, dz = dzk >> 2;
    int d = dz & 3, mat = dz >> 2;
    const float* src = mat ? gw : mw;
    int j0 = jt * 64, n0 = nt * 64;
    int tid = threadIdx.x, tx = tid & 15, ty = tid >> 4;
    float acc[4][4] = {};
    int i0 = kc * 64;
    for (int rep = 0; rep < 16; ++rep) {
        int idx = rep * 256 + tid;
        int r = idx >> 6, cq = idx & 63;
        At[r][cq] = yw[(size_t)(i0 + r) * 256 + j0 + cq];
        Bt[cq][r] = src[(size_t)(n0 + r) * 1024 + d * 256 + i0 + cq];
    }
    __syncthreads();
    for (int ii = 0; ii < 64; ++ii) {
        float4 a4 = *(const float4*)(&At[ii][ty * 4]);
        float4 b4 = *(const float4*)(&Bt[ii][tx * 4]);
        float av[4] = {a4.x, a4.y, a4.z, a4.w};
        float bv[4] = {b4.x, b4.y, b4.z, b4.w};
        for (int q = 0; q < 4; ++q)
            for (int p = 0; p < 4; ++p)
                acc[q][p] = fmaf(av[q], bv[p], acc[q][p]);
    }
    float* dst = WF + (size_t)kc * 512 * 1024;
    for (int q = 0; q < 4; ++q) {
        int k = d * 256 + j0 + ty * 4 + q;
        for (int p = 0; p < 4; ++p) {
            int n = n0 + tx * 4 + p;
            dst[(size_t)(mat * 256 + n) * 1024 + k] = acc[q][p];
        }
    }
}

// sum the 4 split-K partials, round to bf16
__global__ __launch_bounds__(256) void k_foldsum(
    const float* __restrict__ WF, unsigned short* __restrict__ WBT)
{
    int t = blockIdx.x * 256 + threadIdx.x;
    size_t o = (size_t)t * 4;
    const size_t S = (size_t)512 * 1024;
    float4 s0 = *(const float4*)(WF + o);
    float4 s1 = *(const float4*)(WF + S + o);
    float4 s2 = *(const float4*)(WF + 2 * S + o);
    float4 s3 = *(const float4*)(WF + 3 * S + o);
    unsigned short pk[4];
    pk[0] = f2b(s0.x + s1.x + s2.x + s3.x);
    pk[1] = f2b(s0.y + s1.y + s2.y + s3.y);
    pk[2] = f2b(s0.z + s1.z + s2.z + s3.z);
    pk[3] = f2b(s0.w + s1.w + s2.w + s3.w);
    *(unsigned long long*)(&WBT[o]) = *(const unsigned long long*)pk;
}

// ---------------- fused prep: xpose (512) | wprep (32) | owprep (32) | foldbias (128)
__global__ __launch_bounds__(256) void k_prep(
    const float* __restrict__ x, unsigned short* __restrict__ XT,
    const float* __restrict__ xw, const float* __restrict__ bcw, const float* __restrict__ dw,
    unsigned short* __restrict__ WPT,
    const float* __restrict__ ow, unsigned short* __restrict__ OWB,
    const float* __restrict__ mw, const float* __restrict__ gw,
    const float* __restrict__ mb, const float* __restrict__ gb,
    const float* __restrict__ yb,
    float* __restrict__ bm2, float* __restrict__ bg2)
{
    int bid = blockIdx.x;
    int t = threadIdx.x;
    if (bid < 512) {
        int pl = t & 63;
        int grp = t >> 6;
        int p0 = bid * 64;
        int b = p0 >> 14;
        int l = (p0 & (LL - 1)) + pl;
        size_t gp = (size_t)(p0 + pl);
        const float* xr = x + (size_t)b * 96 * LL + l;
        unsigned short* orow = XT + gp * 192;
#pragma unroll
        for (int kk = 0; kk < 3; ++kk) {
            int kq = grp * 3 + kk;
            short8v hi, lo;
#pragma unroll
            for (int c = 0; c < 8; ++c) {
                float v = xr[(size_t)(kq * 8 + c) * LL];
                unsigned short h = f2b(v);
                float r = v - b2f(h);
                hi[c] = (short)h;
                lo[c] = (short)f2b(r);
            }
            *(short8v*)(orow + kq * 8) = hi;
            *(short8v*)(orow + 96 + kq * 8) = lo;
        }
    } else if (bid < 544) {
        int unit = bid - 512;
        int rp = unit * 32 + (t >> 3);
        int sub = t & 7;
        int nn16 = rp >> 6, g = (rp >> 4) & 3, ni = rp & 15;
        int n = nn16 * 16 + ni;
        const float* row;
        if (g == 0)      row = xw + (size_t)n * 96;
        else if (g == 1) row = bcw + (size_t)n * 96;
        else if (g == 2) row = bcw + (size_t)(256 + n) * 96;
        else             row = dw + (size_t)n * 96;
        unsigned short* orow = WPT + (size_t)rp * 192;
        for (int kq = sub; kq < 12; kq += 8) {
            short8v hv;
#pragma unroll
            for (int c = 0; c < 8; ++c) hv[c] = (short)f2b(row[kq * 8 + c]);
            *(short8v*)(orow + kq * 8) = hv;
            *(short8v*)(orow + 96 + kq * 8) = hv;
        }
    } else if (bid < 576) {
        int unit = bid - 544;
        int r = unit * 4 + (t >> 6);
        int lane = t & 63;
        unsigned short pk[4];
        if (r < 96) {
            float4 v = *(const float4*)(ow + (size_t)r * 256 + lane * 4);
            pk[0] = f2b(v.x); pk[1] = f2b(v.y); pk[2] = f2b(v.z); pk[3] = f2b(v.w);
        } else {
            pk[0] = pk[1] = pk[2] = pk[3] = 0;
        }
        *(unsigned long long*)(&OWB[(size_t)r * 256 + lane * 4]) = *(const unsigned long long*)pk;
    } else {
        int unit = bid - 576;
        int row = unit * 4 + (t >> 6);
        int lane = t & 63;
        int n = row & 255;
        const float* W = (row < 256) ? mw : gw;
        float s = 0.f;
        for (int k = lane; k < 1024; k += 64)
            s = fmaf(W[(size_t)n * 1024 + k], yb[k & 255], s);
        for (int off = 32; off; off >>= 1) s += __shfl_down(s, off);
        if (lane == 0) {
            if (row < 256) bm2[n] = s + mb[n];
            else           bg2[n] = s + gb[n];
        }
    }
}

// ---------------- in-projection via MFMA (K=192), dbuf + counted vmcnt
__global__ __launch_bounds__(256) void k_proj_mfma(
    const unsigned short* __restrict__ XT, const unsigned short* __restrict__ WPT,
    const float* __restrict__ xb, const float* __restrict__ bcb, const float* __restrict__ db,
    unsigned int* __restrict__ AB, unsigned short* __restrict__ C)
{
    __shared__ __align__(16) unsigned short smA[2 * 128 * 32];   // 16 KB
    __shared__ __align__(16) unsigned short smB[2 * 128 * 32];   // 16 KB
    int tid = threadIdx.x;
    int w = tid >> 6, l = tid & 63;
    int mt = blockIdx.x;
    int bnt = blockIdx.y;
    int p0 = mt * 128;
    int bn0 = bnt * 128;

    int rowA = tid >> 2;
    int chA  = tid & 3;
    int laneRow = l & 15;
    int laneK   = l >> 4;

    float4v acc[2][8];
#pragma unroll
    for (int i = 0; i < 2; ++i)
#pragma unroll
        for (int f = 0; f < 8; ++f) acc[i][f] = (float4v)0.f;

    auto stage = [&](int kt, int buf) {
        const unsigned short* gA = XT + (size_t)(p0 + rowA) * 192 + kt * 32 + chA * 8;
        const unsigned short* gB = WPT + (size_t)(bn0 + rowA) * 192 + kt * 32 + chA * 8;
        unsigned short* sA = smA + buf * 4096;
        unsigned short* sB = smB + buf * 4096;
        GLL16(gA,            sA + tid * 8);
        GLL16(gA + 64 * 192, sA + 2048 + tid * 8);
        GLL16(gB,            sB + tid * 8);
        GLL16(gB + 64 * 192, sB + 2048 + tid * 8);
    };

    stage(0, 0);

    int cur = 0;
    for (int kt = 0; kt < 6; ++kt) {
        if (kt < 5) {
            stage(kt + 1, cur ^ 1);
            asm volatile("s_waitcnt vmcnt(4)" ::: "memory");
        } else {
            asm volatile("s_waitcnt vmcnt(0)" ::: "memory");
        }
        __builtin_amdgcn_s_barrier();

        const unsigned short* sA = smA + cur * 4096;
        const unsigned short* sB = smB + cur * 4096;
        short8v a0 = *(const short8v*)(&sA[(w * 32 + laneRow) * 32 + laneK * 8]);
        short8v a1 = *(const short8v*)(&sA[(w * 32 + 16 + laneRow) * 32 + laneK * 8]);
#pragma unroll
        for (int f = 0; f < 8; ++f) {
            short8v bf_ = *(const short8v*)(&sB[(f * 16 + laneRow) * 32 + laneK * 8]);
            acc[0][f] = __builtin_amdgcn_mfma_f32_16x16x32_bf16(a0, bf_, acc[0][f], 0, 0, 0);
            acc[1][f] = __builtin_amdgcn_mfma_f32_16x16x32_bf16(a1, bf_, acc[1][f], 0, 0, 0);
        }
        __builtin_amdgcn_s_barrier();
        cur ^= 1;
    }

    int lr = l >> 4, lc = l & 15;
#pragma unroll
    for (int mr = 0; mr < 2; ++mr) {
#pragma unroll
        for (int nn2 = 0; nn2 < 2; ++nn2) {
            int n = (bnt * 2 + nn2) * 16 + lc;
            float xbv = xb[n], bb = bcb[n], cb = bcb[256 + n], dbv = db[n];
#pragma unroll
            for (int q = 0; q < 4; ++q) {
                int p = p0 + w * 32 + mr * 16 + lr * 4 + q;
                float u  = acc[mr][nn2 * 4 + 0][q] + xbv;
                float Bm = acc[mr][nn2 * 4 + 1][q] + bb;
                float Cm = acc[mr][nn2 * 4 + 2][q] + cb;
                float dl = acc[mr][nn2 * 4 + 3][q] + dbv;
                float a  = 1.0f / (1.0f + __expf(dl));
                float bu = (1.0f - a) * Bm * u;
                size_t base = (size_t)p * NLAT + n;
                AB[base] = (unsigned int)f2b(a) | ((unsigned int)f2b(bu) << 16);
                C[base]  = f2b(Cm);
            }
        }
    }
}

__device__ __forceinline__ int src_pos(int d, int t) {
    int s = (d >= 2) ? (LL - 1 - t) : t;
    return (d & 1) ? (((s & 127) << 7) | (s >> 7)) : s;
}

// ---------------- scan pass 1: dir-paired, ILP-2
__global__ __launch_bounds__(256) void k_scan1(
    const unsigned int* __restrict__ AB,
    float* __restrict__ AggA, float* __restrict__ AggB)
{
    int n = threadIdx.x;
    int c = blockIdx.x, dp = blockIdx.y, b = blockIdx.z;
    int d1 = dp, d2 = dp + 2;
    int c2 = NCH - 1 - c;
    int t01 = c * CHU, t02 = c2 * CHU;
    const unsigned int* ABb = AB + (size_t)b * LL * NLAT + n;
    float h1 = 0.f, A1 = 1.f, h2 = 0.f, A2 = 1.f;
#pragma unroll 4
    for (int i = 0; i < CHU; ++i) {
        int ls1 = src_pos(d1, t01 + i);
        int ls2 = src_pos(d2, t02 + i);
        unsigned int v1 = ABb[(size_t)ls1 * NLAT];
        unsigned int v2 = ABb[(size_t)ls2 * NLAT];
        float a1 = __uint_as_float(v1 << 16), bu1 = __uint_as_float(v1 & 0xFFFF0000u);
        float a2 = __uint_as_float(v2 << 16), bu2 = __uint_as_float(v2 & 0xFFFF0000u);
        h1 = fmaf(a1, h1, bu1); A1 *= a1;
        h2 = fmaf(a2, h2, bu2); A2 *= a2;
    }
    size_t o1 = (((size_t)b * 4 + d1) * NCH + c) * NLAT + n;
    size_t o2 = (((size_t)b * 4 + d2) * NCH + c2) * NLAT + n;
    AggA[o1] = A1; AggB[o1] = h1;
    AggA[o2] = A2; AggB[o2] = h2;
}

// ---------------- scan pass 2: Kogge-Stone over NCH chunk-aggregate affine maps
__global__ __launch_bounds__(256) void k_scan2(
    const float* __restrict__ AggA, const float* __restrict__ AggB,
    float* __restrict__ Hs)
{
    __shared__ float sA[NCH];
    __shared__ float sB[NCH];
    int n = blockIdx.x;
    int d = blockIdx.y, b = blockIdx.z;
    int c = threadIdx.x;
    size_t o = (((size_t)b * 4 + d) * NCH + c) * NLAT + n;
    sA[c] = AggA[o];
    sB[c] = AggB[o];
    __syncthreads();
#pragma unroll
    for (int st = 1; st < NCH; st <<= 1) {
        float pA = 1.f, pB = 0.f;
        if (c >= st) { pA = sA[c - st]; pB = sB[c - st]; }
        __syncthreads();
        if (c >= st) {
            float aO = sA[c];
            sB[c] = fmaf(aO, pB, sB[c]);
            sA[c] = aO * pA;
        }
        __syncthreads();
    }
    Hs[o] = (c == 0) ? 0.f : sB[c - 1];
}

// ---------------- scan pass 3: dir-paired replay, ILP-2, y = C*h
__global__ __launch_bounds__(256) void k_scan3(
    const unsigned int* __restrict__ AB, const unsigned short* __restrict__ C,
    const float* __restrict__ Hs, unsigned short* __restrict__ ys)
{
    int n = threadIdx.x;
    int c = blockIdx.x, dp = blockIdx.y, b = blockIdx.z;
    int d1 = dp, d2 = dp + 2;
    int c2 = NCH - 1 - c;
    int t01 = c * CHU, t02 = c2 * CHU;
    const unsigned int* ABb = AB + (size_t)b * LL * NLAT + n;
    const unsigned short* Cb = C + (size_t)b * LL * NLAT + n;
    size_t o1 = (((size_t)b * 4 + d1) * NCH + c) * NLAT + n;
    size_t o2 = (((size_t)b * 4 + d2) * NCH + c2) * NLAT + n;
    float h1 = Hs[o1], h2 = Hs[o2];
    size_t yb1 = (((size_t)b * 4 + d1) * LL + t01) * NLAT + n;
    size_t yb2 = (((size_t)b * 4 + d2) * LL + t02) * NLAT + n;
#pragma unroll 4
    for (int i = 0; i < CHU; ++i) {
        int ls1 = src_pos(d1, t01 + i);
        int ls2 = src_pos(d2, t02 + i);
        size_t i1 = (size_t)ls1 * NLAT, i2 = (size_t)ls2 * NLAT;
        unsigned int v1 = ABb[i1];
        unsigned int v2 = ABb[i2];
        float a1 = __uint_as_float(v1 << 16), bu1 = __uint_as_float(v1 & 0xFFFF0000u);
        float a2 = __uint_as_float(v2 << 16), bu2 = __uint_as_float(v2 & 0xFFFF0000u);
        h1 = fmaf(a1, h1, bu1);
        h2 = fmaf(a2, h2, bu2);
        float y1 = b2f(Cb[i1]) * h1;
        float y2 = b2f(Cb[i2]) * h2;
        ys[yb1 + (size_t)i * NLAT] = f2b(y1);
        ys[yb2 + (size_t)i * NLAT] = f2b(y2);
    }
}

// ---------------- merge (MFMA bf16) — validated round-11 template (2-dbuf, vmcnt(6))
__global__ __launch_bounds__(256) void k_merge_mfma(
    const unsigned short* __restrict__ ys,
    const unsigned short* __restrict__ WBT,
    const float* __restrict__ bm2, const float* __restrict__ bg2,
    unsigned short* __restrict__ z)
{
    __shared__ __align__(16) unsigned short smA[2 * 128 * 32];   // 16 KB
    __shared__ __align__(16) unsigned short smB[2 * 256 * 32];   // 32 KB
    int tid = threadIdx.x;
    int w = tid >> 6, l = tid & 63;
    int wm = w >> 1, wn = w & 1;
    int mt = blockIdx.x;
    int nt = blockIdx.y;
    int p0 = mt * 128;
    int b4 = (p0 >> 14) * 4;
    int l0 = p0 & (LL - 1);
    int n0 = nt * 128;

    int rS = tid >> 2;
    int cg = (tid & 3) ^ ((rS >> 1) & 3);
    int laneRow = l & 15;
    int laneK   = l >> 4;
    int rx = (laneRow >> 1) & 3;

    float4v accM[4][4], accG[4][4];
#pragma unroll
    for (int i = 0; i < 4; ++i)
#pragma unroll
        for (int j = 0; j < 4; ++j) { accM[i][j] = (float4v)0.f; accG[i][j] = (float4v)0.f; }

    auto stage = [&](int kt, int buf) {
        int d = kt >> 3;
        int j0k = (kt & 7) * 32;
        const unsigned short* gAb = ys + (((size_t)(b4 + d)) * LL + l0) * 256 + j0k + cg * 8;
        unsigned short* sA = smA + buf * 4096;
        unsigned short* sB = smB + buf * 8192;
#pragma unroll
        for (int rep = 0; rep < 2; ++rep) {
            GLL16(gAb + (size_t)(rep * 64 + rS) * 256, sA + rep * 2048 + tid * 8);
        }
#pragma unroll
        for (int rep = 0; rep < 4; ++rep) {
            int rr = rep * 64 + rS;
            int nrow = (rr < 128) ? (n0 + rr) : (256 + n0 + rr - 128);
            GLL16(WBT + (size_t)nrow * 1024 + kt * 32 + cg * 8, sB + rep * 2048 + tid * 8);
        }
    };

    stage(0, 0);

    int cur = 0;
    for (int kt = 0; kt < 32; ++kt) {
        if (kt < 31) {
            stage(kt + 1, cur ^ 1);
            asm volatile("s_waitcnt vmcnt(6)" ::: "memory");
        } else {
            asm volatile("s_waitcnt vmcnt(0)" ::: "memory");
        }
        __builtin_amdgcn_s_barrier();

        const unsigned short* sA = smA + cur * 4096;
        const unsigned short* sB = smB + cur * 8192;
        int cxo = (laneK ^ rx) * 8;
        short8v a[4];
#pragma unroll
        for (int mr = 0; mr < 4; ++mr)
            a[mr] = *(const short8v*)(&sA[(wm * 64 + mr * 16 + laneRow) * 32 + cxo]);
#pragma unroll
        for (int nr = 0; nr < 4; ++nr) {
            short8v bm_ = *(const short8v*)(&sB[(wn * 64 + nr * 16 + laneRow) * 32 + cxo]);
            short8v bg_ = *(const short8v*)(&sB[(128 + wn * 64 + nr * 16 + laneRow) * 32 + cxo]);
#pragma unroll
            for (int mr = 0; mr < 4; ++mr) {
                accM[mr][nr] = __builtin_amdgcn_mfma_f32_16x16x32_bf16(a[mr], bm_, accM[mr][nr], 0, 0, 0);
                accG[mr][nr] = __builtin_amdgcn_mfma_f32_16x16x32_bf16(a[mr], bg_, accG[mr][nr], 0, 0, 0);
            }
        }
        __builtin_amdgcn_s_barrier();
        cur ^= 1;
    }

    int lr = l >> 4, lc = l & 15;
#pragma unroll
    for (int mr = 0; mr < 4; ++mr) {
#pragma unroll
        for (int nr = 0; nr < 4; ++nr) {
            int n = n0 + wn * 64 + nr * 16 + lc;
            float bmv = bm2[n], bgv = bg2[n];
#pragma unroll
            for (int q = 0; q < 4; ++q) {
                int p = p0 + wm * 64 + mr * 16 + lr * 4 + q;
                float m = accM[mr][nr][q] + bmv;
                float g = accG[mr][nr][q] + bgv;
                float zv = m / (1.f + __expf(-g));
                z[(size_t)p * NLAT + n] = f2b(zv);
            }
        }
    }
}

// ---------------- out projection via MFMA (K=256), dbuf + counted vmcnt
__global__ __launch_bounds__(256) void k_out_mfma(
    const unsigned short* __restrict__ z, const unsigned short* __restrict__ OWB,
    const float* __restrict__ ob, float* __restrict__ out)
{
    __shared__ __align__(16) unsigned short smA[2 * 128 * 32];
    __shared__ __align__(16) unsigned short smB[2 * 128 * 32];
    int tid = threadIdx.x;
    int w = tid >> 6, l = tid & 63;
    int p0 = blockIdx.x * 128;
    int b = p0 >> 14;
    int l0 = p0 & (LL - 1);

    int rowA = tid >> 2;
    int chA  = tid & 3;
    int laneRow = l & 15;
    int laneK   = l >> 4;

    float4v acc[2][6];
#pragma unroll
    for (int i = 0; i < 2; ++i)
#pragma unroll
        for (int f = 0; f < 6; ++f) acc[i][f] = (float4v)0.f;

    auto stage = [&](int kt, int buf) {
        const unsigned short* gA = z + (size_t)(p0 + rowA) * 256 + kt * 32 + chA * 8;
        const unsigned short* gB = OWB + (size_t)rowA * 256 + kt * 32 + chA * 8;
        unsigned short* sA = smA + buf * 4096;
        unsigned short* sB = smB + buf * 4096;
        GLL16(gA,            sA + tid * 8);
        GLL16(gA + 64 * 256, sA + 2048 + tid * 8);
        GLL16(gB,            sB + tid * 8);
        GLL16(gB + 64 * 256, sB + 2048 + tid * 8);
    };

    stage(0, 0);

    int cur = 0;
    for (int kt = 0; kt < 8; ++kt) {
        if (kt < 7) {
            stage(kt + 1, cur ^ 1);
            asm volatile("s_waitcnt vmcnt(4)" ::: "memory");
        } else {
            asm volatile("s_waitcnt vmcnt(0)" ::: "memory");
        }
        __builtin_amdgcn_s_barrier();

        const unsigned short* sA = smA + cur * 4096;
        const unsigned short* sB = smB + cur * 4096;
        short8v a0 = *(const short8v*)(&sA[(w * 32 + laneRow) * 32 + laneK * 8]);
        short8v a1 = *(const short8v*)(&sA[(w * 32 + 16 + laneRow) * 32 + laneK * 8]);
#pragma unroll
        for (int nr = 0; nr < 6; ++nr) {
            short8v bf_ = *(const short8v*)(&sB[(nr * 16 + laneRow) * 32 + laneK * 8]);
            acc[0][nr] = __builtin_amdgcn_mfma_f32_16x16x32_bf16(a0, bf_, acc[0][nr], 0, 0, 0);
            acc[1][nr] = __builtin_amdgcn_mfma_f32_16x16x32_bf16(a1, bf_, acc[1][nr], 0, 0, 0);
        }
        __builtin_amdgcn_s_barrier();
        cur ^= 1;
    }

    int lr = l >> 4, lc = l & 15;
#pragma unroll
    for (int mr = 0; mr < 2; ++mr) {
#pragma unroll
        for (int nr = 0; nr < 6; ++nr) {
            int c = nr * 16 + lc;
            float obv = ob[c];
            int ll = l0 + w * 32 + mr * 16 + lr * 4;
            float4 v;
            v.x = acc[mr][nr][0] + obv;
            v.y = acc[mr][nr][1] + obv;
            v.z = acc[mr][nr][2] + obv;
            v.w = acc[mr][nr][3] + obv;
            *(float4*)(&out[((size_t)(b * 96 + c)) * LL + ll]) = v;
        }
    }
}

extern "C" void kernel_launch(void* const* d_in, const int* in_sizes, int n_in,
                              void* d_out, int out_size, void* d_ws, size_t ws_size,
                              hipStream_t stream) {
    (void)in_sizes; (void)n_in; (void)out_size; (void)ws_size;
    const float* x   = (const float*)d_in[0];
    const float* xw  = (const float*)d_in[1];
    const float* xb  = (const float*)d_in[2];
    const float* bcw = (const float*)d_in[3];
    const float* bcb = (const float*)d_in[4];
    const float* dw  = (const float*)d_in[5];
    const float* db  = (const float*)d_in[6];
    const float* yw  = (const float*)d_in[7];
    const float* yb  = (const float*)d_in[8];
    const float* mw  = (const float*)d_in[9];
    const float* mb  = (const float*)d_in[10];
    const float* gw  = (const float*)d_in[11];
    const float* gb  = (const float*)d_in[12];
    const float* ow  = (const float*)d_in[13];
    const float* ob  = (const float*)d_in[14];
    float* out = (float*)d_out;

    char* ws = (char*)d_ws;
    size_t off = 0;
    auto alloc = [&](size_t bytes) -> void* {
        void* p = ws + off;
        off += (bytes + 255) & ~(size_t)255;
        return p;
    };
    unsigned int*   AB  = (unsigned int*)  alloc((size_t)NB * LL * NLAT * 4);
    unsigned short* C   = (unsigned short*)alloc((size_t)NB * LL * NLAT * 2);
    unsigned short* YS  = (unsigned short*)alloc((size_t)NB * 4 * LL * NLAT * 2);
    unsigned short* Z   = (unsigned short*)alloc((size_t)NB * LL * NLAT * 2);
    unsigned short* WBT = (unsigned short*)alloc((size_t)512 * 1024 * 2);
    unsigned short* XT  = (unsigned short*)alloc((size_t)NB * LL * 192 * 2);
    unsigned short* WPT = (unsigned short*)alloc((size_t)1024 * 192 * 2);
    unsigned short* OWB = (unsigned short*)alloc((size_t)128 * 256 * 2);
    float* WF   = (float*)alloc((size_t)4 * 512 * 1024 * 4);
    float* BM2  = (float*)alloc(256 * 4);
    float* BG2  = (float*)alloc(256 * 4);
    float* AggA = (float*)alloc((size_t)NB * 4 * NCH * NLAT * 4);
    float* AggB = (float*)alloc((size_t)NB * 4 * NCH * NLAT * 4);
    float* HS   = (float*)alloc((size_t)NB * 4 * NCH * NLAT * 4);

    k_foldw_part<<<dim3(4, 4, 32),    256, 0, stream>>>(yw, mw, gw, WF);
    k_foldsum   <<<512,               256, 0, stream>>>(WF, WBT);
    k_prep      <<<704,               256, 0, stream>>>(x, XT, xw, bcw, dw, WPT,
                                                        ow, OWB, mw, gw, mb, gb, yb, BM2, BG2);
    k_proj_mfma <<<dim3(256, 8),      256, 0, stream>>>(XT, WPT, xb, bcb, db, AB, C);
    k_scan1     <<<dim3(NCH, 2, NB),  256, 0, stream>>>(AB, AggA, AggB);
    k_scan2     <<<dim3(NLAT, 4, NB), 256, 0, stream>>>(AggA, AggB, HS);
    k_scan3     <<<dim3(NCH, 2, NB),  256, 0, stream>>>(AB, C, HS, YS);
    k_merge_mfma<<<dim3(256, 2),      256, 0, stream>>>(YS, WBT, BM2, BG2, Z);
    k_out_mfma  <<<256,               256, 0, stream>>>(Z, OWB, ob, out);
}